// Round 3
// baseline (1227.669 us; speedup 1.0000x reference)
//
#include <hip/hip_runtime.h>

#define NSLOT 32
#define BN_EPS 1e-5f
#define CAP 2048            // bucket capacity (mean ~1024 edges, +32 sigma)
#define BKBITS 6
#define BKN 64              // nodes per bucket

static inline int cdiv_h(int a, int b) { return (a + b - 1) / b; }

__device__ __forceinline__ float4 f4add(float4 a, float4 b) {
    return make_float4(a.x + b.x, a.y + b.y, a.z + b.z, a.w + b.w);
}

// ---------------- edge bucketing: group edges by dst>>6 ----------------
// packed entry: (dst&63)<<26 | src   (requires N < 2^26)

__global__ __launch_bounds__(256) void k_bucket_scatter(const int* __restrict__ src, const int* __restrict__ dst,
                                                        int* __restrict__ bcnt, unsigned* __restrict__ ebuf, int E) {
    int i = blockIdx.x * 256 + threadIdx.x;
    if (i < E) {
        int d = dst[i];
        int s = src[i];
        int b = d >> BKBITS;
        int pos = atomicAdd(&bcnt[b * 16], 1);   // stride 16: one counter per 64B line
        if (pos < CAP) ebuf[(size_t)b * CAP + pos] = ((unsigned)(d & (BKN - 1)) << 26) | (unsigned)s;
    }
}

// ---------------- graph boundaries (graph_id sorted) ----------------

__global__ __launch_bounds__(256) void k_gstart(const int* __restrict__ gid, int* __restrict__ gstart, int n, int G) {
    int i = blockIdx.x * 256 + threadIdx.x;
    if (i >= n) return;
    int g = gid[i];
    int gp = (i == 0) ? -1 : gid[i - 1];
    for (int x = gp + 1; x <= g; ++x) gstart[x] = i;
    if (i == n - 1) { for (int x = g + 1; x <= G; ++x) gstart[x] = n; }
}

// ---------------- per-node transform: p = (relu(a*y+c)) @ W  (or h @ W for layer 0) ----------------

template <int AFF>
__global__ __launch_bounds__(256) void k_transform(const float* __restrict__ xin, const float* __restrict__ W,
                                                   const float* __restrict__ cA, const float* __restrict__ cC,
                                                   float* __restrict__ p, int n) {
    __shared__ float sW[32][32];
    __shared__ float sA[32], sC[32];
    int t = threadIdx.x;
    for (int i = t; i < 1024; i += 256) sW[i >> 5][i & 31] = W[i];
    if (AFF && t < 32) { sA[t] = cA[t]; sC[t] = cC[t]; }
    __syncthreads();
    int node = blockIdx.x * 256 + t;
    if (node >= n) return;
    float x[32];
    const float4* s4 = (const float4*)(xin + (size_t)node * 32);
#pragma unroll
    for (int q = 0; q < 8; q++) {
        float4 v = s4[q];
        x[4*q] = v.x; x[4*q+1] = v.y; x[4*q+2] = v.z; x[4*q+3] = v.w;
    }
    if (AFF) {
#pragma unroll
        for (int k = 0; k < 32; k++) {
            float v = sA[k] * x[k] + sC[k];
            x[k] = v > 0.f ? v : 0.f;
        }
    }
    float acc[32];
#pragma unroll
    for (int f = 0; f < 32; f++) acc[f] = 0.f;
#pragma unroll
    for (int k = 0; k < 32; k++) {
        float xv = x[k];
#pragma unroll
        for (int f = 0; f < 32; f++) acc[f] += xv * sW[k][f];
    }
    float4* d4 = (float4*)(p + (size_t)node * 32);
#pragma unroll
    for (int q = 0; q < 8; q++) d4[q] = make_float4(acc[4*q], acc[4*q+1], acc[4*q+2], acc[4*q+3]);
}

// layer 3: p3[v] = relu(a*y2+c) . w3   (scalar per node)
__global__ __launch_bounds__(256) void k_transform3(const float* __restrict__ y2, const float* __restrict__ w3,
                                                    const float* __restrict__ cA, const float* __restrict__ cC,
                                                    float* __restrict__ p3, int n) {
    __shared__ float sw[32], sA[32], sC[32];
    int t = threadIdx.x;
    if (t < 32) { sw[t] = w3[t]; sA[t] = cA[t]; sC[t] = cC[t]; }
    __syncthreads();
    int i = blockIdx.x * 256 + t;
    if (i >= n) return;
    const float4* x4 = (const float4*)(y2 + (size_t)i * 32);
    float acc = 0.f;
#pragma unroll
    for (int q = 0; q < 8; q++) {
        float4 v = x4[q];
        float vv[4] = {v.x, v.y, v.z, v.w};
#pragma unroll
        for (int r = 0; r < 4; r++) {
            int k = q * 4 + r;
            float xv = sA[k] * vv[r] + sC[k];
            xv = xv > 0.f ? xv : 0.f;
            acc += xv * sw[k];
        }
    }
    p3[i] = acc;
}

// ---------------- bucket aggregation: y[v] = mean_{u->v} p[u] + bias; fused deg count + BN stats ----
// one block per bucket (64 nodes); 32 groups x 8 lanes; LDS float accumulators.

__global__ __launch_bounds__(256) void k_bucket_agg(const float4* __restrict__ p4, const unsigned* __restrict__ ebuf,
                                                    const int* __restrict__ bcnt, const float* __restrict__ bias,
                                                    float4* __restrict__ y4, float* __restrict__ sSum,
                                                    float* __restrict__ sSq, int N) {
    __shared__ float accf[BKN][33];   // +1 pad: bank = (dl + c) % 32, spread by dl
    __shared__ int cnt64[BKN];
    __shared__ float sS[32][32], sQ[32][32];
    int t = threadIdx.x;
    int b = blockIdx.x;
    for (int i = t; i < BKN * 33; i += 256) ((float*)accf)[i] = 0.f;
    if (t < BKN) cnt64[t] = 0;
    __syncthreads();

    int cnt = bcnt[b * 16]; if (cnt > CAP) cnt = CAP;
    int lane = t & 7, grp = t >> 3;
    const unsigned* eb = ebuf + (size_t)b * CAP;
    int chunk = (((cnt + 31) >> 5) + 3) & ~3;     // per-group contiguous chunk, multiple of 4
    int start = grp * chunk;
    int end = start + chunk; if (end > cnt) end = cnt;

    int j = start;
    for (; j + 4 <= end; j += 4) {
        uint4 e4 = *(const uint4*)(eb + j);
        unsigned s0 = e4.x & 0x3FFFFFFu, s1 = e4.y & 0x3FFFFFFu,
                 s2 = e4.z & 0x3FFFFFFu, s3 = e4.w & 0x3FFFFFFu;
        int d0 = e4.x >> 26, d1 = e4.y >> 26, d2 = e4.z >> 26, d3 = e4.w >> 26;
        float4 g0 = p4[(size_t)s0 * 8 + lane];
        float4 g1 = p4[(size_t)s1 * 8 + lane];
        float4 g2 = p4[(size_t)s2 * 8 + lane];
        float4 g3 = p4[(size_t)s3 * 8 + lane];
        if (lane == 0) {
            atomicAdd(&cnt64[d0], 1); atomicAdd(&cnt64[d1], 1);
            atomicAdd(&cnt64[d2], 1); atomicAdd(&cnt64[d3], 1);
        }
        int c = lane * 4;
        atomicAdd(&accf[d0][c+0], g0.x); atomicAdd(&accf[d0][c+1], g0.y);
        atomicAdd(&accf[d0][c+2], g0.z); atomicAdd(&accf[d0][c+3], g0.w);
        atomicAdd(&accf[d1][c+0], g1.x); atomicAdd(&accf[d1][c+1], g1.y);
        atomicAdd(&accf[d1][c+2], g1.z); atomicAdd(&accf[d1][c+3], g1.w);
        atomicAdd(&accf[d2][c+0], g2.x); atomicAdd(&accf[d2][c+1], g2.y);
        atomicAdd(&accf[d2][c+2], g2.z); atomicAdd(&accf[d2][c+3], g2.w);
        atomicAdd(&accf[d3][c+0], g3.x); atomicAdd(&accf[d3][c+1], g3.y);
        atomicAdd(&accf[d3][c+2], g3.z); atomicAdd(&accf[d3][c+3], g3.w);
    }
    for (; j < end; ++j) {
        unsigned e = eb[j];
        unsigned s = e & 0x3FFFFFFu;
        int dl = e >> 26;
        float4 g = p4[(size_t)s * 8 + lane];
        if (lane == 0) atomicAdd(&cnt64[dl], 1);
        int c = lane * 4;
        atomicAdd(&accf[dl][c+0], g.x); atomicAdd(&accf[dl][c+1], g.y);
        atomicAdd(&accf[dl][c+2], g.z); atomicAdd(&accf[dl][c+3], g.w);
    }
    __syncthreads();

    // writeout + BN partials: thread t covers (node, node+32) for channels sub*4..+3
    int sub = t & 7, nd = t >> 3;   // nd 0..31
    float4 bias4 = ((const float4*)bias)[sub];
    float4 s4 = make_float4(0.f, 0.f, 0.f, 0.f);
    float4 q4 = s4;
#pragma unroll
    for (int rep = 0; rep < 2; rep++) {
        int node = nd + rep * 32;
        int gnode = b * BKN + node;
        if (gnode < N) {
            int c = cnt64[node];
            float inv = (c > 0) ? 1.f / (float)c : 1.f;
            float4 v;
            v.x = accf[node][sub*4+0] * inv + bias4.x;
            v.y = accf[node][sub*4+1] * inv + bias4.y;
            v.z = accf[node][sub*4+2] * inv + bias4.z;
            v.w = accf[node][sub*4+3] * inv + bias4.w;
            y4[(size_t)gnode * 8 + sub] = v;
            s4 = f4add(s4, v);
            q4 = f4add(q4, make_float4(v.x*v.x, v.y*v.y, v.z*v.z, v.w*v.w));
        }
    }
    *(float4*)&sS[nd][sub*4] = s4;
    *(float4*)&sQ[nd][sub*4] = q4;
    __syncthreads();
    if (t < 32) {
        float S = 0.f, Q = 0.f;
#pragma unroll
        for (int r = 0; r < 32; r++) { S += sS[r][t]; Q += sQ[r][t]; }
        int slot = blockIdx.x & (NSLOT - 1);
        atomicAdd(&sSum[slot * 32 + t], S);
        atomicAdd(&sSq[slot * 32 + t], Q);
    }
}

// scalar variant for layer 3 (channels = 1)
__global__ __launch_bounds__(256) void k_bucket_agg3(const float* __restrict__ p3, const unsigned* __restrict__ ebuf,
                                                     const int* __restrict__ bcnt, const float* __restrict__ b1,
                                                     float* __restrict__ y3, float* __restrict__ sSum,
                                                     float* __restrict__ sSq, int N) {
    __shared__ float acc3[BKN];
    __shared__ int cnt3[BKN];
    int t = threadIdx.x, b = blockIdx.x;
    if (t < BKN) { acc3[t] = 0.f; cnt3[t] = 0; }
    __syncthreads();
    int cnt = bcnt[b * 16]; if (cnt > CAP) cnt = CAP;
    const unsigned* eb = ebuf + (size_t)b * CAP;
    for (int j = t; j < cnt; j += 256) {
        unsigned e = eb[j];
        float v = p3[e & 0x3FFFFFFu];
        int dl = e >> 26;
        atomicAdd(&acc3[dl], v);
        atomicAdd(&cnt3[dl], 1);
    }
    __syncthreads();
    if (t < 64) {
        float lsum = 0.f, lsq = 0.f;
        int gnode = b * BKN + t;
        if (gnode < N) {
            int c = cnt3[t];
            float inv = (c > 0) ? 1.f / (float)c : 1.f;
            float v = acc3[t] * inv + b1[0];
            y3[gnode] = v; lsum = v; lsq = v * v;
        }
        for (int off = 32; off > 0; off >>= 1) {
            lsum += __shfl_down(lsum, off, 64);
            lsq  += __shfl_down(lsq,  off, 64);
        }
        if (t == 0) {
            int slot = blockIdx.x & (NSLOT - 1);
            atomicAdd(&sSum[slot * 32], lsum);
            atomicAdd(&sSq[slot * 32], lsq);
        }
    }
}

// ---------------- BN stat finalize -> affine coefs ----------------

__global__ void k_stats(const float* __restrict__ sSum, const float* __restrict__ sSq,
                        const float* __restrict__ g, const float* __restrict__ b,
                        float* __restrict__ cA, float* __restrict__ cC, int C, float invN) {
    int f = threadIdx.x;
    if (f < C) {
        float S = 0.f, Q = 0.f;
        for (int s = 0; s < NSLOT; s++) { S += sSum[s * 32 + f]; Q += sSq[s * 32 + f]; }
        float m = S * invN;
        float var = Q * invN - m * m;
        if (var < 0.f) var = 0.f;
        float inv = rsqrtf(var + BN_EPS);
        float a = g[f] * inv;
        cA[f] = a;
        cC[f] = b[f] - m * a;
    }
}

// ---------------- per-graph mean pool + MLP ----------------
// 256 threads = 8 node-slots x 32 lanes; lane -> (array, float4-chunk); coalesced float4 reads.

__global__ __launch_bounds__(256) void k_pool_mlp(const float* __restrict__ h, const float* __restrict__ y0,
                                                  const float* __restrict__ y1, const float* __restrict__ y2,
                                                  const float* __restrict__ y3, const float* __restrict__ cA,
                                                  const float* __restrict__ cC, const int* __restrict__ gstart,
                                                  const float* __restrict__ w0, const float* __restrict__ b0,
                                                  const float* __restrict__ w1, const float* __restrict__ b1,
                                                  const float* __restrict__ w2, const float* __restrict__ b2,
                                                  float* __restrict__ out) {
    int g = blockIdx.x;
    int t = threadIdx.x;
    int s0 = gstart[g], s1 = gstart[g + 1];
    int lane = t & 31, slot = t >> 5;
    int arr = lane >> 3, sub = lane & 7;
    const float* bases0 = (arr == 0) ? h : (arr == 1) ? y0 : (arr == 2) ? y1 : y2;
    const float4* bp = (const float4*)bases0;
    float4 a4 = make_float4(1.f, 1.f, 1.f, 1.f);
    float4 c4 = make_float4(0.f, 0.f, 0.f, 0.f);
    bool aff = (arr > 0);
    if (aff) {
        a4 = ((const float4*)cA)[(arr - 1) * 8 + sub];
        c4 = ((const float4*)cC)[(arr - 1) * 8 + sub];
    }
    float4 acc = make_float4(0.f, 0.f, 0.f, 0.f);
    for (int n = s0 + slot; n < s1; n += 8) {
        float4 v = bp[(size_t)n * 8 + sub];
        if (aff) {
            float vx = fmaf(a4.x, v.x, c4.x); vx = vx > 0.f ? vx : 0.f;
            float vy = fmaf(a4.y, v.y, c4.y); vy = vy > 0.f ? vy : 0.f;
            float vz = fmaf(a4.z, v.z, c4.z); vz = vz > 0.f ? vz : 0.f;
            float vw = fmaf(a4.w, v.w, c4.w); vw = vw > 0.f ? vw : 0.f;
            v = make_float4(vx, vy, vz, vw);
        }
        acc = f4add(acc, v);
    }
    __shared__ float sP[8][128];
    __shared__ float sY[8];
    ((float4*)&sP[slot][lane * 4])[0] = acc;
    if (t < 8) {
        float a = cA[96], c = cC[96], s = 0.f;
        for (int n = s0 + t; n < s1; n += 8) {
            float v = fmaf(a, y3[n], c);
            s += v > 0.f ? v : 0.f;
        }
        sY[t] = s;
    }
    __syncthreads();
    __shared__ float hg[129];
    __shared__ float hid1[128];
    __shared__ float hid2[64];
    float inv = (s1 > s0) ? 1.f / (float)(s1 - s0) : 1.f;
    if (t < 128) {
        float S = 0.f;
#pragma unroll
        for (int s = 0; s < 8; s++) S += sP[s][t];
        hg[t] = S * inv;
    } else if (t == 128) {
        float S = 0.f;
#pragma unroll
        for (int s = 0; s < 8; s++) S += sY[s];
        hg[128] = S * inv;
    }
    __syncthreads();
    if (t < 128) {
        float a = b0[t];
        for (int i = 0; i < 129; i++) a += hg[i] * w0[i * 128 + t];
        hid1[t] = a > 0.f ? a : 0.f;
    }
    __syncthreads();
    if (t < 64) {
        float a = b1[t];
        for (int i = 0; i < 128; i++) a += hid1[i] * w1[i * 64 + t];
        hid2[t] = a > 0.f ? a : 0.f;
    }
    __syncthreads();
    if (t < 64) {
        float v = hid2[t] * w2[t];
        for (int off = 32; off > 0; off >>= 1) v += __shfl_down(v, off, 64);
        if (t == 0) out[g] = v + b2[0];
    }
}

// ---------------- launcher ----------------

extern "C" void kernel_launch(void* const* d_in, const int* in_sizes, int n_in,
                              void* d_out, int out_size, void* d_ws, size_t ws_size,
                              hipStream_t stream) {
    const float* h   = (const float*)d_in[0];
    const int* src   = (const int*)d_in[1];
    const int* dst   = (const int*)d_in[2];
    const int* gid   = (const int*)d_in[3];
    const float* convw[4], *convb[4], *bng[4], *bnb[4];
    for (int i = 0; i < 4; i++) {
        convw[i] = (const float*)d_in[4 + 4 * i];
        convb[i] = (const float*)d_in[5 + 4 * i];
        bng[i]   = (const float*)d_in[6 + 4 * i];
        bnb[i]   = (const float*)d_in[7 + 4 * i];
    }
    const float* mw0 = (const float*)d_in[20];
    const float* mb0 = (const float*)d_in[21];
    const float* mw1 = (const float*)d_in[22];
    const float* mb1 = (const float*)d_in[23];
    const float* mw2 = (const float*)d_in[24];
    const float* mb2 = (const float*)d_in[25];

    const int N = in_sizes[0] / 32;
    const int E = in_sizes[1];
    const int G = out_size;
    const int NBUCK = cdiv_h(N, BKN);

    // workspace bump allocator (512B aligned)
    char* ws = (char*)d_ws;
    size_t off = 0;
    auto alloc = [&](size_t bytes) -> void* {
        void* p = ws + off;
        off += (bytes + 511) & ~(size_t)511;
        return p;
    };
    int* bcnt      = (int*)alloc((size_t)NBUCK * 16 * 4);       // padded: 1 counter / 64B line
    unsigned* ebuf = (unsigned*)alloc((size_t)NBUCK * CAP * 4);
    int* gstart    = (int*)alloc((size_t)(G + 1) * 4);
    float* p    = (float*)alloc((size_t)N * 32 * 4);
    float* y0   = (float*)alloc((size_t)N * 32 * 4);
    float* y1   = (float*)alloc((size_t)N * 32 * 4);
    float* y2   = (float*)alloc((size_t)N * 32 * 4);
    float* y3   = (float*)alloc((size_t)N * 4);
    float* sSum = (float*)alloc((size_t)4 * NSLOT * 32 * 4);
    float* sSq  = (float*)alloc((size_t)4 * NSLOT * 32 * 4);
    float* cAa  = (float*)alloc((size_t)4 * 32 * 4);
    float* cCc  = (float*)alloc((size_t)4 * 32 * 4);
    (void)ws_size; (void)n_in;

    const int NB_E = cdiv_h(E, 256);
    const int NB_N = cdiv_h(N, 256);
    const float invN = 1.f / (float)N;

    hipMemsetAsync(bcnt, 0, (size_t)NBUCK * 16 * 4, stream);
    hipMemsetAsync(sSum, 0, (size_t)4 * NSLOT * 32 * 4, stream);
    hipMemsetAsync(sSq, 0, (size_t)4 * NSLOT * 32 * 4, stream);

    k_bucket_scatter<<<NB_E, 256, 0, stream>>>(src, dst, bcnt, ebuf, E);
    k_gstart<<<NB_N, 256, 0, stream>>>(gid, gstart, N, G);

    // layer 0
    k_transform<0><<<NB_N, 256, 0, stream>>>(h, convw[0], nullptr, nullptr, p, N);
    k_bucket_agg<<<NBUCK, 256, 0, stream>>>((const float4*)p, ebuf, bcnt, convb[0], (float4*)y0,
                                            sSum + 0 * NSLOT * 32, sSq + 0 * NSLOT * 32, N);
    k_stats<<<1, 32, 0, stream>>>(sSum + 0 * NSLOT * 32, sSq + 0 * NSLOT * 32, bng[0], bnb[0], cAa + 0, cCc + 0, 32, invN);
    // layer 1
    k_transform<1><<<NB_N, 256, 0, stream>>>(y0, convw[1], cAa + 0, cCc + 0, p, N);
    k_bucket_agg<<<NBUCK, 256, 0, stream>>>((const float4*)p, ebuf, bcnt, convb[1], (float4*)y1,
                                            sSum + 1 * NSLOT * 32, sSq + 1 * NSLOT * 32, N);
    k_stats<<<1, 32, 0, stream>>>(sSum + 1 * NSLOT * 32, sSq + 1 * NSLOT * 32, bng[1], bnb[1], cAa + 32, cCc + 32, 32, invN);
    // layer 2
    k_transform<1><<<NB_N, 256, 0, stream>>>(y1, convw[2], cAa + 32, cCc + 32, p, N);
    k_bucket_agg<<<NBUCK, 256, 0, stream>>>((const float4*)p, ebuf, bcnt, convb[2], (float4*)y2,
                                            sSum + 2 * NSLOT * 32, sSq + 2 * NSLOT * 32, N);
    k_stats<<<1, 32, 0, stream>>>(sSum + 2 * NSLOT * 32, sSq + 2 * NSLOT * 32, bng[2], bnb[2], cAa + 64, cCc + 64, 32, invN);
    // layer 3 (32 -> 1, pre-multiplied so the gather is scalar)
    k_transform3<<<NB_N, 256, 0, stream>>>(y2, convw[3], cAa + 64, cCc + 64, (float*)p, N);
    k_bucket_agg3<<<NBUCK, 256, 0, stream>>>((float*)p, ebuf, bcnt, convb[3], y3,
                                             sSum + 3 * NSLOT * 32, sSq + 3 * NSLOT * 32, N);
    k_stats<<<1, 32, 0, stream>>>(sSum + 3 * NSLOT * 32, sSq + 3 * NSLOT * 32, bng[3], bnb[3], cAa + 96, cCc + 96, 1, invN);

    // pooling + MLP
    k_pool_mlp<<<G, 256, 0, stream>>>(h, y0, y1, y2, y3, cAa, cCc, gstart,
                                      mw0, mb0, mw1, mb1, mw2, mb2, (float*)d_out);
}

// Round 4
// 407.108 us; speedup vs baseline: 3.0156x; 3.0156x over previous
//
#include <hip/hip_runtime.h>

#define NSLOT 32
#define BN_EPS 1e-5f
#define CAP 2048            // bucket capacity (mean ~1024 edges at E/N=16, +32 sigma)
#define BKBITS 6
#define BKN 64              // nodes per bucket

static inline int cdiv_h(int a, int b) { return (a + b - 1) / b; }

__device__ __forceinline__ float4 f4add(float4 a, float4 b) {
    return make_float4(a.x + b.x, a.y + b.y, a.z + b.z, a.w + b.w);
}

// ---------------- phase 1: bucket edges by dst>>6 (line-dense append) ----------------
// packed entry: (dst&63)<<26 | src   (requires N < 2^26)

__global__ __launch_bounds__(256) void k_bucket_scatter(const int* __restrict__ src, const int* __restrict__ dst,
                                                        int* __restrict__ bcnt, unsigned* __restrict__ ebuf, int E) {
    int i = blockIdx.x * 256 + threadIdx.x;
    if (i < E) {
        int d = dst[i];
        int s = src[i];
        int b = d >> BKBITS;
        int pos = atomicAdd(&bcnt[b * 16], 1);   // stride 16: one counter per 64B line
        if (pos < CAP) ebuf[(size_t)b * CAP + pos] = ((unsigned)(d & (BKN - 1)) << 26) | (unsigned)s;
    }
}

// ---------------- phase 2: per-bucket counting sort -> node-grouped col + rs/re ----------------

__global__ __launch_bounds__(256) void k_local_sort(const unsigned* __restrict__ ebuf, const int* __restrict__ bcnt,
                                                    int* __restrict__ col, int* __restrict__ rs, int* __restrict__ re,
                                                    int N) {
    __shared__ int binCnt[BKN], binStart[BKN], cursor[BKN];
    int t = threadIdx.x, b = blockIdx.x;
    if (t < BKN) { binCnt[t] = 0; cursor[t] = 0; }
    __syncthreads();
    int cnt = bcnt[b * 16]; if (cnt > CAP) cnt = CAP;
    const unsigned* eb = ebuf + (size_t)b * CAP;
    for (int j = t; j < cnt; j += 256) atomicAdd(&binCnt[eb[j] >> 26], 1);
    __syncthreads();
    if (t < BKN) {                       // exclusive scan over 64 bins (wave 0)
        int v = binCnt[t];
        int incl = v;
        for (int off = 1; off < BKN; off <<= 1) {
            int o = __shfl_up(incl, off, 64);
            if (t >= off) incl += o;
        }
        binStart[t] = incl - v;
    }
    __syncthreads();
    int base = b * CAP;
    for (int j = t; j < cnt; j += 256) {
        unsigned e = eb[j];
        int l = e >> 26;
        int pos = binStart[l] + atomicAdd(&cursor[l], 1);
        col[base + pos] = (int)(e & 0x3FFFFFFu);
    }
    if (t < BKN) {
        int gnode = b * BKN + t;
        if (gnode < N) {
            rs[gnode] = base + binStart[t];
            re[gnode] = base + binStart[t] + binCnt[t];
        }
    }
}

// ---------------- graph boundaries (graph_id sorted) ----------------

__global__ __launch_bounds__(256) void k_gstart(const int* __restrict__ gid, int* __restrict__ gstart, int n, int G) {
    int i = blockIdx.x * 256 + threadIdx.x;
    if (i >= n) return;
    int g = gid[i];
    int gp = (i == 0) ? -1 : gid[i - 1];
    for (int x = gp + 1; x <= g; ++x) gstart[x] = i;
    if (i == n - 1) { for (int x = g + 1; x <= G; ++x) gstart[x] = n; }
}

// ---------------- per-node transform: p = (relu(a*y+c)) @ W  (or h @ W for layer 0) ----------------

template <int AFF>
__global__ __launch_bounds__(256) void k_transform(const float* __restrict__ xin, const float* __restrict__ W,
                                                   const float* __restrict__ cA, const float* __restrict__ cC,
                                                   float* __restrict__ p, int n) {
    __shared__ float sW[32][32];
    __shared__ float sA[32], sC[32];
    int t = threadIdx.x;
    for (int i = t; i < 1024; i += 256) sW[i >> 5][i & 31] = W[i];
    if (AFF && t < 32) { sA[t] = cA[t]; sC[t] = cC[t]; }
    __syncthreads();
    int node = blockIdx.x * 256 + t;
    if (node >= n) return;
    float x[32];
    const float4* s4 = (const float4*)(xin + (size_t)node * 32);
#pragma unroll
    for (int q = 0; q < 8; q++) {
        float4 v = s4[q];
        x[4*q] = v.x; x[4*q+1] = v.y; x[4*q+2] = v.z; x[4*q+3] = v.w;
    }
    if (AFF) {
#pragma unroll
        for (int k = 0; k < 32; k++) {
            float v = sA[k] * x[k] + sC[k];
            x[k] = v > 0.f ? v : 0.f;
        }
    }
    float acc[32];
#pragma unroll
    for (int f = 0; f < 32; f++) acc[f] = 0.f;
#pragma unroll
    for (int k = 0; k < 32; k++) {
        float xv = x[k];
#pragma unroll
        for (int f = 0; f < 32; f++) acc[f] += xv * sW[k][f];
    }
    float4* d4 = (float4*)(p + (size_t)node * 32);
#pragma unroll
    for (int q = 0; q < 8; q++) d4[q] = make_float4(acc[4*q], acc[4*q+1], acc[4*q+2], acc[4*q+3]);
}

// layer 3: p3[v] = relu(a*y2+c) . w3   (scalar per node)
__global__ __launch_bounds__(256) void k_transform3(const float* __restrict__ y2, const float* __restrict__ w3,
                                                    const float* __restrict__ cA, const float* __restrict__ cC,
                                                    float* __restrict__ p3, int n) {
    __shared__ float sw[32], sA[32], sC[32];
    int t = threadIdx.x;
    if (t < 32) { sw[t] = w3[t]; sA[t] = cA[t]; sC[t] = cC[t]; }
    __syncthreads();
    int i = blockIdx.x * 256 + t;
    if (i >= n) return;
    const float4* x4 = (const float4*)(y2 + (size_t)i * 32);
    float acc = 0.f;
#pragma unroll
    for (int q = 0; q < 8; q++) {
        float4 v = x4[q];
        float vv[4] = {v.x, v.y, v.z, v.w};
#pragma unroll
        for (int r = 0; r < 4; r++) {
            int k = q * 4 + r;
            float xv = sA[k] * vv[r] + sC[k];
            xv = xv > 0.f ? xv : 0.f;
            acc += xv * sw[k];
        }
    }
    p3[i] = acc;
}

// ---------------- aggregation: y[v] = mean_{u->v} p[u] + bias; fused BN stats ----------------
// 8 lanes/node (float4 per lane), one node per 8-lane group, 4-deep unrolled register gather.

__global__ __launch_bounds__(256) void k_aggregate(const float4* __restrict__ p4, const int* __restrict__ rs,
                                                   const int* __restrict__ re, const int* __restrict__ col,
                                                   const float* __restrict__ bias,
                                                   float4* __restrict__ y4, float* __restrict__ sSum,
                                                   float* __restrict__ sSq, int n) {
    int t = threadIdx.x;
    int lane = t & 7;          // float4 slot within the 32 channels
    int grp = t >> 3;          // 0..31 : node within block
    int node = blockIdx.x * 32 + grp;
    float4 vout = make_float4(0.f, 0.f, 0.f, 0.f);
    if (node < n) {
        int s0 = rs[node], s1 = re[node];
        float4 a0 = vout, a1 = vout, a2 = vout, a3 = vout;
        int j = s0;
        for (; j + 4 <= s1; j += 4) {
            int c0 = col[j], c1 = col[j + 1], c2 = col[j + 2], c3 = col[j + 3];
            float4 g0 = p4[(size_t)c0 * 8 + lane];
            float4 g1 = p4[(size_t)c1 * 8 + lane];
            float4 g2 = p4[(size_t)c2 * 8 + lane];
            float4 g3 = p4[(size_t)c3 * 8 + lane];
            a0 = f4add(a0, g0); a1 = f4add(a1, g1); a2 = f4add(a2, g2); a3 = f4add(a3, g3);
        }
        for (; j < s1; ++j) {
            int c = col[j];
            a0 = f4add(a0, p4[(size_t)c * 8 + lane]);
        }
        float4 s = f4add(f4add(a0, a1), f4add(a2, a3));
        int deg = s1 - s0;
        float inv = (deg > 0) ? 1.f / (float)deg : 1.f;
        float4 b = ((const float4*)bias)[lane];
        vout = make_float4(s.x * inv + b.x, s.y * inv + b.y, s.z * inv + b.z, s.w * inv + b.w);
        y4[(size_t)node * 8 + lane] = vout;
    }
    // BN stats: channel = lane*4+k
    __shared__ float sS[32][32];
    __shared__ float sQ[32][32];
    ((float4*)&sS[grp][lane * 4])[0] = vout;
    ((float4*)&sQ[grp][lane * 4])[0] = make_float4(vout.x * vout.x, vout.y * vout.y,
                                                   vout.z * vout.z, vout.w * vout.w);
    __syncthreads();
    if (t < 32) {
        float S = 0.f, Q = 0.f;
#pragma unroll
        for (int g2 = 0; g2 < 32; g2++) { S += sS[g2][t]; Q += sQ[g2][t]; }
        int slot = blockIdx.x & (NSLOT - 1);
        atomicAdd(&sSum[slot * 32 + t], S);
        atomicAdd(&sSq[slot * 32 + t], Q);
    }
}

__global__ __launch_bounds__(256) void k_aggregate3(const float* __restrict__ p3, const int* __restrict__ rs,
                                                    const int* __restrict__ re, const int* __restrict__ col,
                                                    const float* __restrict__ b1,
                                                    float* __restrict__ y3, float* __restrict__ sSum,
                                                    float* __restrict__ sSq, int n) {
    int i = blockIdx.x * 256 + threadIdx.x;
    float lsum = 0.f, lsq = 0.f;
    if (i < n) {
        int s0 = rs[i], s1 = re[i];
        float a0 = 0.f, a1 = 0.f, a2 = 0.f, a3 = 0.f;
        int j = s0;
        for (; j + 4 <= s1; j += 4) {
            int c0 = col[j], c1 = col[j + 1], c2 = col[j + 2], c3 = col[j + 3];
            a0 += p3[c0]; a1 += p3[c1]; a2 += p3[c2]; a3 += p3[c3];
        }
        for (; j < s1; ++j) a0 += p3[col[j]];
        float acc = (a0 + a1) + (a2 + a3);
        float inv = (s1 > s0) ? 1.f / (float)(s1 - s0) : 1.f;
        float v = acc * inv + b1[0];
        y3[i] = v; lsum = v; lsq = v * v;
    }
    __shared__ float sS[256], sQ[256];
    int t = threadIdx.x;
    sS[t] = lsum; sQ[t] = lsq;
    __syncthreads();
    for (int s = 128; s > 0; s >>= 1) {
        if (t < s) { sS[t] += sS[t + s]; sQ[t] += sQ[t + s]; }
        __syncthreads();
    }
    if (t == 0) {
        int slot = blockIdx.x & (NSLOT - 1);
        atomicAdd(&sSum[slot * 32], sS[0]);
        atomicAdd(&sSq[slot * 32], sQ[0]);
    }
}

// ---------------- BN stat finalize -> affine coefs ----------------

__global__ void k_stats(const float* __restrict__ sSum, const float* __restrict__ sSq,
                        const float* __restrict__ g, const float* __restrict__ b,
                        float* __restrict__ cA, float* __restrict__ cC, int C, float invN) {
    int f = threadIdx.x;
    if (f < C) {
        float S = 0.f, Q = 0.f;
        for (int s = 0; s < NSLOT; s++) { S += sSum[s * 32 + f]; Q += sSq[s * 32 + f]; }
        float m = S * invN;
        float var = Q * invN - m * m;
        if (var < 0.f) var = 0.f;
        float inv = rsqrtf(var + BN_EPS);
        float a = g[f] * inv;
        cA[f] = a;
        cC[f] = b[f] - m * a;
    }
}

// ---------------- per-graph mean pool + MLP ----------------
// 256 threads = 8 node-slots x 32 lanes; lane -> (array, float4-chunk); coalesced float4 reads.

__global__ __launch_bounds__(256) void k_pool_mlp(const float* __restrict__ h, const float* __restrict__ y0,
                                                  const float* __restrict__ y1, const float* __restrict__ y2,
                                                  const float* __restrict__ y3, const float* __restrict__ cA,
                                                  const float* __restrict__ cC, const int* __restrict__ gstart,
                                                  const float* __restrict__ w0, const float* __restrict__ b0,
                                                  const float* __restrict__ w1, const float* __restrict__ b1,
                                                  const float* __restrict__ w2, const float* __restrict__ b2,
                                                  float* __restrict__ out) {
    int g = blockIdx.x;
    int t = threadIdx.x;
    int s0 = gstart[g], s1 = gstart[g + 1];
    int lane = t & 31, slot = t >> 5;
    int arr = lane >> 3, sub = lane & 7;
    const float* bases0 = (arr == 0) ? h : (arr == 1) ? y0 : (arr == 2) ? y1 : y2;
    const float4* bp = (const float4*)bases0;
    float4 a4 = make_float4(1.f, 1.f, 1.f, 1.f);
    float4 c4 = make_float4(0.f, 0.f, 0.f, 0.f);
    bool aff = (arr > 0);
    if (aff) {
        a4 = ((const float4*)cA)[(arr - 1) * 8 + sub];
        c4 = ((const float4*)cC)[(arr - 1) * 8 + sub];
    }
    float4 acc = make_float4(0.f, 0.f, 0.f, 0.f);
    for (int n = s0 + slot; n < s1; n += 8) {
        float4 v = bp[(size_t)n * 8 + sub];
        if (aff) {
            float vx = fmaf(a4.x, v.x, c4.x); vx = vx > 0.f ? vx : 0.f;
            float vy = fmaf(a4.y, v.y, c4.y); vy = vy > 0.f ? vy : 0.f;
            float vz = fmaf(a4.z, v.z, c4.z); vz = vz > 0.f ? vz : 0.f;
            float vw = fmaf(a4.w, v.w, c4.w); vw = vw > 0.f ? vw : 0.f;
            v = make_float4(vx, vy, vz, vw);
        }
        acc = f4add(acc, v);
    }
    __shared__ float sP[8][128];
    __shared__ float sY[8];
    ((float4*)&sP[slot][lane * 4])[0] = acc;
    if (t < 8) {
        float a = cA[96], c = cC[96], s = 0.f;
        for (int n = s0 + t; n < s1; n += 8) {
            float v = fmaf(a, y3[n], c);
            s += v > 0.f ? v : 0.f;
        }
        sY[t] = s;
    }
    __syncthreads();
    __shared__ float hg[129];
    __shared__ float hid1[128];
    __shared__ float hid2[64];
    float inv = (s1 > s0) ? 1.f / (float)(s1 - s0) : 1.f;
    if (t < 128) {
        float S = 0.f;
#pragma unroll
        for (int s = 0; s < 8; s++) S += sP[s][t];
        hg[t] = S * inv;
    } else if (t == 128) {
        float S = 0.f;
#pragma unroll
        for (int s = 0; s < 8; s++) S += sY[s];
        hg[128] = S * inv;
    }
    __syncthreads();
    if (t < 128) {
        float a = b0[t];
        for (int i = 0; i < 129; i++) a += hg[i] * w0[i * 128 + t];
        hid1[t] = a > 0.f ? a : 0.f;
    }
    __syncthreads();
    if (t < 64) {
        float a = b1[t];
        for (int i = 0; i < 128; i++) a += hid1[i] * w1[i * 64 + t];
        hid2[t] = a > 0.f ? a : 0.f;
    }
    __syncthreads();
    if (t < 64) {
        float v = hid2[t] * w2[t];
        for (int off = 32; off > 0; off >>= 1) v += __shfl_down(v, off, 64);
        if (t == 0) out[g] = v + b2[0];
    }
}

// ---------------- launcher ----------------

extern "C" void kernel_launch(void* const* d_in, const int* in_sizes, int n_in,
                              void* d_out, int out_size, void* d_ws, size_t ws_size,
                              hipStream_t stream) {
    const float* h   = (const float*)d_in[0];
    const int* src   = (const int*)d_in[1];
    const int* dst   = (const int*)d_in[2];
    const int* gid   = (const int*)d_in[3];
    const float* convw[4], *convb[4], *bng[4], *bnb[4];
    for (int i = 0; i < 4; i++) {
        convw[i] = (const float*)d_in[4 + 4 * i];
        convb[i] = (const float*)d_in[5 + 4 * i];
        bng[i]   = (const float*)d_in[6 + 4 * i];
        bnb[i]   = (const float*)d_in[7 + 4 * i];
    }
    const float* mw0 = (const float*)d_in[20];
    const float* mb0 = (const float*)d_in[21];
    const float* mw1 = (const float*)d_in[22];
    const float* mb1 = (const float*)d_in[23];
    const float* mw2 = (const float*)d_in[24];
    const float* mb2 = (const float*)d_in[25];

    const int N = in_sizes[0] / 32;
    const int E = in_sizes[1];
    const int G = out_size;
    const int NBUCK = cdiv_h(N, BKN);

    // workspace bump allocator (512B aligned)
    char* ws = (char*)d_ws;
    size_t off = 0;
    auto alloc = [&](size_t bytes) -> void* {
        void* p = ws + off;
        off += (bytes + 511) & ~(size_t)511;
        return p;
    };
    int* bcnt      = (int*)alloc((size_t)NBUCK * 16 * 4);       // padded: 1 counter / 64B line
    unsigned* ebuf = (unsigned*)alloc((size_t)NBUCK * CAP * 4);
    int* col       = (int*)alloc((size_t)NBUCK * CAP * 4);
    int* rs        = (int*)alloc((size_t)N * 4);
    int* re        = (int*)alloc((size_t)N * 4);
    int* gstart    = (int*)alloc((size_t)(G + 1) * 4);
    float* p    = (float*)alloc((size_t)N * 32 * 4);
    float* y0   = (float*)alloc((size_t)N * 32 * 4);
    float* y1   = (float*)alloc((size_t)N * 32 * 4);
    float* y2   = (float*)alloc((size_t)N * 32 * 4);
    float* y3   = (float*)alloc((size_t)N * 4);
    float* sSum = (float*)alloc((size_t)4 * NSLOT * 32 * 4);
    float* sSq  = (float*)alloc((size_t)4 * NSLOT * 32 * 4);
    float* cAa  = (float*)alloc((size_t)4 * 32 * 4);
    float* cCc  = (float*)alloc((size_t)4 * 32 * 4);
    (void)ws_size; (void)n_in;

    const int NB_E = cdiv_h(E, 256);
    const int NB_N = cdiv_h(N, 256);
    const int NB_AG = cdiv_h(N, 32);   // one node per 8-lane group
    const float invN = 1.f / (float)N;

    hipMemsetAsync(bcnt, 0, (size_t)NBUCK * 16 * 4, stream);
    hipMemsetAsync(sSum, 0, (size_t)4 * NSLOT * 32 * 4, stream);
    hipMemsetAsync(sSq, 0, (size_t)4 * NSLOT * 32 * 4, stream);

    // edge grouping: bucket append + per-bucket counting sort (replaces hist/scan/fill CSR build)
    k_bucket_scatter<<<NB_E, 256, 0, stream>>>(src, dst, bcnt, ebuf, E);
    k_local_sort<<<NBUCK, 256, 0, stream>>>(ebuf, bcnt, col, rs, re, N);
    k_gstart<<<NB_N, 256, 0, stream>>>(gid, gstart, N, G);

    // layer 0
    k_transform<0><<<NB_N, 256, 0, stream>>>(h, convw[0], nullptr, nullptr, p, N);
    k_aggregate<<<NB_AG, 256, 0, stream>>>((const float4*)p, rs, re, col, convb[0], (float4*)y0,
                                           sSum + 0 * NSLOT * 32, sSq + 0 * NSLOT * 32, N);
    k_stats<<<1, 32, 0, stream>>>(sSum + 0 * NSLOT * 32, sSq + 0 * NSLOT * 32, bng[0], bnb[0], cAa + 0, cCc + 0, 32, invN);
    // layer 1
    k_transform<1><<<NB_N, 256, 0, stream>>>(y0, convw[1], cAa + 0, cCc + 0, p, N);
    k_aggregate<<<NB_AG, 256, 0, stream>>>((const float4*)p, rs, re, col, convb[1], (float4*)y1,
                                           sSum + 1 * NSLOT * 32, sSq + 1 * NSLOT * 32, N);
    k_stats<<<1, 32, 0, stream>>>(sSum + 1 * NSLOT * 32, sSq + 1 * NSLOT * 32, bng[1], bnb[1], cAa + 32, cCc + 32, 32, invN);
    // layer 2
    k_transform<1><<<NB_N, 256, 0, stream>>>(y1, convw[2], cAa + 32, cCc + 32, p, N);
    k_aggregate<<<NB_AG, 256, 0, stream>>>((const float4*)p, rs, re, col, convb[2], (float4*)y2,
                                           sSum + 2 * NSLOT * 32, sSq + 2 * NSLOT * 32, N);
    k_stats<<<1, 32, 0, stream>>>(sSum + 2 * NSLOT * 32, sSq + 2 * NSLOT * 32, bng[2], bnb[2], cAa + 64, cCc + 64, 32, invN);
    // layer 3 (32 -> 1, pre-multiplied so the gather is scalar)
    k_transform3<<<NB_N, 256, 0, stream>>>(y2, convw[3], cAa + 64, cCc + 64, (float*)p, N);
    k_aggregate3<<<NB_N, 256, 0, stream>>>((float*)p, rs, re, col, convb[3], y3,
                                           sSum + 3 * NSLOT * 32, sSq + 3 * NSLOT * 32, N);
    k_stats<<<1, 32, 0, stream>>>(sSum + 3 * NSLOT * 32, sSq + 3 * NSLOT * 32, bng[3], bnb[3], cAa + 96, cCc + 96, 1, invN);

    // pooling + MLP
    k_pool_mlp<<<G, 256, 0, stream>>>(h, y0, y1, y2, y3, cAa, cCc, gstart,
                                      mw0, mb0, mw1, mb1, mw2, mb2, (float*)d_out);
}

// Round 5
// 378.102 us; speedup vs baseline: 3.2469x; 1.0767x over previous
//
#include <hip/hip_runtime.h>

#define NSLOT 32
#define BN_EPS 1e-5f
#define NPART 8             // scatter partitions (~XCDs)
#define CAP_P 256           // per (bucket,partition) capacity (mean ~128, +11 sigma)
#define CAP 2048            // per-bucket total capacity for sorted col
#define BKBITS 6
#define BKN 64              // nodes per bucket

static inline int cdiv_h(int a, int b) { return (a + b - 1) / b; }

__device__ __forceinline__ float4 f4add(float4 a, float4 b) {
    return make_float4(a.x + b.x, a.y + b.y, a.z + b.z, a.w + b.w);
}

// ---------------- phase 1: bucket edges by dst>>6, 8-way partitioned by blockIdx&7 ----------------
// packed entry: (dst&63)<<26 | src   (requires N < 2^26)
// Partitioning keeps each open 64B line owned by ~one XCD (no cross-XCD partial-line
// writeback amplification) and cuts per-counter atomic contention 8x.

__global__ __launch_bounds__(256) void k_bucket_scatter(const int* __restrict__ src, const int* __restrict__ dst,
                                                        int* __restrict__ bcnt, unsigned* __restrict__ ebuf, int E) {
    int i = blockIdx.x * 256 + threadIdx.x;
    int part = blockIdx.x & (NPART - 1);
    if (i < E) {
        int d = dst[i];
        int s = src[i];
        int b = d >> BKBITS;
        int pos = atomicAdd(&bcnt[(b * NPART + part) * 16], 1);   // stride 16: one counter per 64B line
        if (pos < CAP_P)
            ebuf[((size_t)b * NPART + part) * CAP_P + pos] =
                ((unsigned)(d & (BKN - 1)) << 26) | (unsigned)s;
    }
}

// ---------------- phase 2: per-bucket counting sort over 8 sub-lists -> node-grouped col + rs/re ----

__global__ __launch_bounds__(256) void k_local_sort(const unsigned* __restrict__ ebuf, const int* __restrict__ bcnt,
                                                    int* __restrict__ col, int* __restrict__ rs, int* __restrict__ re,
                                                    int N) {
    __shared__ int binCnt[BKN], binStart[BKN], cursor[BKN];
    __shared__ int pcnt[NPART];
    int t = threadIdx.x, b = blockIdx.x;
    if (t < BKN) { binCnt[t] = 0; cursor[t] = 0; }
    if (t < NPART) {
        int c = bcnt[(b * NPART + t) * 16];
        pcnt[t] = c > CAP_P ? CAP_P : c;
    }
    __syncthreads();
    const unsigned* eb = ebuf + (size_t)b * NPART * CAP_P;
#pragma unroll
    for (int p = 0; p < NPART; p++) {
        int c = pcnt[p];
        for (int j = t; j < c; j += 256) atomicAdd(&binCnt[eb[p * CAP_P + j] >> 26], 1);
    }
    __syncthreads();
    if (t < BKN) {                       // exclusive scan over 64 bins (wave 0)
        int v = binCnt[t];
        int incl = v;
        for (int off = 1; off < BKN; off <<= 1) {
            int o = __shfl_up(incl, off, 64);
            if (t >= off) incl += o;
        }
        binStart[t] = incl - v;
    }
    __syncthreads();
    int base = b * CAP;
#pragma unroll
    for (int p = 0; p < NPART; p++) {
        int c = pcnt[p];
        for (int j = t; j < c; j += 256) {
            unsigned e = eb[p * CAP_P + j];
            int l = e >> 26;
            int pos = binStart[l] + atomicAdd(&cursor[l], 1);
            col[base + pos] = (int)(e & 0x3FFFFFFu);
        }
    }
    if (t < BKN) {
        int gnode = b * BKN + t;
        if (gnode < N) {
            rs[gnode] = base + binStart[t];
            re[gnode] = base + binStart[t] + binCnt[t];
        }
    }
}

// ---------------- graph boundaries (graph_id sorted) ----------------

__global__ __launch_bounds__(256) void k_gstart(const int* __restrict__ gid, int* __restrict__ gstart, int n, int G) {
    int i = blockIdx.x * 256 + threadIdx.x;
    if (i >= n) return;
    int g = gid[i];
    int gp = (i == 0) ? -1 : gid[i - 1];
    for (int x = gp + 1; x <= g; ++x) gstart[x] = i;
    if (i == n - 1) { for (int x = g + 1; x <= G; ++x) gstart[x] = n; }
}

// ---------------- per-node transform: p = (relu(a*y+c)) @ W  (or h @ W for layer 0) ----------------

template <int AFF>
__global__ __launch_bounds__(256) void k_transform(const float* __restrict__ xin, const float* __restrict__ W,
                                                   const float* __restrict__ cA, const float* __restrict__ cC,
                                                   float* __restrict__ p, int n) {
    __shared__ float sW[32][32];
    __shared__ float sA[32], sC[32];
    int t = threadIdx.x;
    for (int i = t; i < 1024; i += 256) sW[i >> 5][i & 31] = W[i];
    if (AFF && t < 32) { sA[t] = cA[t]; sC[t] = cC[t]; }
    __syncthreads();
    int node = blockIdx.x * 256 + t;
    if (node >= n) return;
    float x[32];
    const float4* s4 = (const float4*)(xin + (size_t)node * 32);
#pragma unroll
    for (int q = 0; q < 8; q++) {
        float4 v = s4[q];
        x[4*q] = v.x; x[4*q+1] = v.y; x[4*q+2] = v.z; x[4*q+3] = v.w;
    }
    if (AFF) {
#pragma unroll
        for (int k = 0; k < 32; k++) {
            float v = sA[k] * x[k] + sC[k];
            x[k] = v > 0.f ? v : 0.f;
        }
    }
    float acc[32];
#pragma unroll
    for (int f = 0; f < 32; f++) acc[f] = 0.f;
#pragma unroll
    for (int k = 0; k < 32; k++) {
        float xv = x[k];
#pragma unroll
        for (int f = 0; f < 32; f++) acc[f] += xv * sW[k][f];
    }
    float4* d4 = (float4*)(p + (size_t)node * 32);
#pragma unroll
    for (int q = 0; q < 8; q++) d4[q] = make_float4(acc[4*q], acc[4*q+1], acc[4*q+2], acc[4*q+3]);
}

// layer 3: p3[v] = relu(a*y2+c) . w3   (scalar per node)
__global__ __launch_bounds__(256) void k_transform3(const float* __restrict__ y2, const float* __restrict__ w3,
                                                    const float* __restrict__ cA, const float* __restrict__ cC,
                                                    float* __restrict__ p3, int n) {
    __shared__ float sw[32], sA[32], sC[32];
    int t = threadIdx.x;
    if (t < 32) { sw[t] = w3[t]; sA[t] = cA[t]; sC[t] = cC[t]; }
    __syncthreads();
    int i = blockIdx.x * 256 + t;
    if (i >= n) return;
    const float4* x4 = (const float4*)(y2 + (size_t)i * 32);
    float acc = 0.f;
#pragma unroll
    for (int q = 0; q < 8; q++) {
        float4 v = x4[q];
        float vv[4] = {v.x, v.y, v.z, v.w};
#pragma unroll
        for (int r = 0; r < 4; r++) {
            int k = q * 4 + r;
            float xv = sA[k] * vv[r] + sC[k];
            xv = xv > 0.f ? xv : 0.f;
            acc += xv * sw[k];
        }
    }
    p3[i] = acc;
}

// ---------------- aggregation: y[v] = mean_{u->v} p[u] + bias; fused BN stats ----------------
// 8 lanes/node (float4 per lane), one node per 8-lane group, 4-deep unrolled register gather.

__global__ __launch_bounds__(256) void k_aggregate(const float4* __restrict__ p4, const int* __restrict__ rs,
                                                   const int* __restrict__ re, const int* __restrict__ col,
                                                   const float* __restrict__ bias,
                                                   float4* __restrict__ y4, float* __restrict__ sSum,
                                                   float* __restrict__ sSq, int n) {
    int t = threadIdx.x;
    int lane = t & 7;          // float4 slot within the 32 channels
    int grp = t >> 3;          // 0..31 : node within block
    int node = blockIdx.x * 32 + grp;
    float4 vout = make_float4(0.f, 0.f, 0.f, 0.f);
    if (node < n) {
        int s0 = rs[node], s1 = re[node];
        float4 a0 = vout, a1 = vout, a2 = vout, a3 = vout;
        int j = s0;
        for (; j + 4 <= s1; j += 4) {
            int c0 = col[j], c1 = col[j + 1], c2 = col[j + 2], c3 = col[j + 3];
            float4 g0 = p4[(size_t)c0 * 8 + lane];
            float4 g1 = p4[(size_t)c1 * 8 + lane];
            float4 g2 = p4[(size_t)c2 * 8 + lane];
            float4 g3 = p4[(size_t)c3 * 8 + lane];
            a0 = f4add(a0, g0); a1 = f4add(a1, g1); a2 = f4add(a2, g2); a3 = f4add(a3, g3);
        }
        for (; j < s1; ++j) {
            int c = col[j];
            a0 = f4add(a0, p4[(size_t)c * 8 + lane]);
        }
        float4 s = f4add(f4add(a0, a1), f4add(a2, a3));
        int deg = s1 - s0;
        float inv = (deg > 0) ? 1.f / (float)deg : 1.f;
        float4 b = ((const float4*)bias)[lane];
        vout = make_float4(s.x * inv + b.x, s.y * inv + b.y, s.z * inv + b.z, s.w * inv + b.w);
        y4[(size_t)node * 8 + lane] = vout;
    }
    // BN stats: channel = lane*4+k
    __shared__ float sS[32][32];
    __shared__ float sQ[32][32];
    ((float4*)&sS[grp][lane * 4])[0] = vout;
    ((float4*)&sQ[grp][lane * 4])[0] = make_float4(vout.x * vout.x, vout.y * vout.y,
                                                   vout.z * vout.z, vout.w * vout.w);
    __syncthreads();
    if (t < 32) {
        float S = 0.f, Q = 0.f;
#pragma unroll
        for (int g2 = 0; g2 < 32; g2++) { S += sS[g2][t]; Q += sQ[g2][t]; }
        int slot = blockIdx.x & (NSLOT - 1);
        atomicAdd(&sSum[slot * 32 + t], S);
        atomicAdd(&sSq[slot * 32 + t], Q);
    }
}

__global__ __launch_bounds__(256) void k_aggregate3(const float* __restrict__ p3, const int* __restrict__ rs,
                                                    const int* __restrict__ re, const int* __restrict__ col,
                                                    const float* __restrict__ b1,
                                                    float* __restrict__ y3, float* __restrict__ sSum,
                                                    float* __restrict__ sSq, int n) {
    int i = blockIdx.x * 256 + threadIdx.x;
    float lsum = 0.f, lsq = 0.f;
    if (i < n) {
        int s0 = rs[i], s1 = re[i];
        float a0 = 0.f, a1 = 0.f, a2 = 0.f, a3 = 0.f;
        int j = s0;
        for (; j + 4 <= s1; j += 4) {
            int c0 = col[j], c1 = col[j + 1], c2 = col[j + 2], c3 = col[j + 3];
            a0 += p3[c0]; a1 += p3[c1]; a2 += p3[c2]; a3 += p3[c3];
        }
        for (; j < s1; ++j) a0 += p3[col[j]];
        float acc = (a0 + a1) + (a2 + a3);
        float inv = (s1 > s0) ? 1.f / (float)(s1 - s0) : 1.f;
        float v = acc * inv + b1[0];
        y3[i] = v; lsum = v; lsq = v * v;
    }
    __shared__ float sS[256], sQ[256];
    int t = threadIdx.x;
    sS[t] = lsum; sQ[t] = lsq;
    __syncthreads();
    for (int s = 128; s > 0; s >>= 1) {
        if (t < s) { sS[t] += sS[t + s]; sQ[t] += sQ[t + s]; }
        __syncthreads();
    }
    if (t == 0) {
        int slot = blockIdx.x & (NSLOT - 1);
        atomicAdd(&sSum[slot * 32], sS[0]);
        atomicAdd(&sSq[slot * 32], sQ[0]);
    }
}

// ---------------- BN stat finalize -> affine coefs ----------------

__global__ void k_stats(const float* __restrict__ sSum, const float* __restrict__ sSq,
                        const float* __restrict__ g, const float* __restrict__ b,
                        float* __restrict__ cA, float* __restrict__ cC, int C, float invN) {
    int f = threadIdx.x;
    if (f < C) {
        float S = 0.f, Q = 0.f;
        for (int s = 0; s < NSLOT; s++) { S += sSum[s * 32 + f]; Q += sSq[s * 32 + f]; }
        float m = S * invN;
        float var = Q * invN - m * m;
        if (var < 0.f) var = 0.f;
        float inv = rsqrtf(var + BN_EPS);
        float a = g[f] * inv;
        cA[f] = a;
        cC[f] = b[f] - m * a;
    }
}

// ---------------- per-graph mean pool + MLP ----------------
// 256 threads = 8 node-slots x 32 lanes; lane -> (array, float4-chunk); coalesced float4 reads.

__global__ __launch_bounds__(256) void k_pool_mlp(const float* __restrict__ h, const float* __restrict__ y0,
                                                  const float* __restrict__ y1, const float* __restrict__ y2,
                                                  const float* __restrict__ y3, const float* __restrict__ cA,
                                                  const float* __restrict__ cC, const int* __restrict__ gstart,
                                                  const float* __restrict__ w0, const float* __restrict__ b0,
                                                  const float* __restrict__ w1, const float* __restrict__ b1,
                                                  const float* __restrict__ w2, const float* __restrict__ b2,
                                                  float* __restrict__ out) {
    int g = blockIdx.x;
    int t = threadIdx.x;
    int s0 = gstart[g], s1 = gstart[g + 1];
    int lane = t & 31, slot = t >> 5;
    int arr = lane >> 3, sub = lane & 7;
    const float* bases0 = (arr == 0) ? h : (arr == 1) ? y0 : (arr == 2) ? y1 : y2;
    const float4* bp = (const float4*)bases0;
    float4 a4 = make_float4(1.f, 1.f, 1.f, 1.f);
    float4 c4 = make_float4(0.f, 0.f, 0.f, 0.f);
    bool aff = (arr > 0);
    if (aff) {
        a4 = ((const float4*)cA)[(arr - 1) * 8 + sub];
        c4 = ((const float4*)cC)[(arr - 1) * 8 + sub];
    }
    float4 acc = make_float4(0.f, 0.f, 0.f, 0.f);
    for (int n = s0 + slot; n < s1; n += 8) {
        float4 v = bp[(size_t)n * 8 + sub];
        if (aff) {
            float vx = fmaf(a4.x, v.x, c4.x); vx = vx > 0.f ? vx : 0.f;
            float vy = fmaf(a4.y, v.y, c4.y); vy = vy > 0.f ? vy : 0.f;
            float vz = fmaf(a4.z, v.z, c4.z); vz = vz > 0.f ? vz : 0.f;
            float vw = fmaf(a4.w, v.w, c4.w); vw = vw > 0.f ? vw : 0.f;
            v = make_float4(vx, vy, vz, vw);
        }
        acc = f4add(acc, v);
    }
    __shared__ float sP[8][128];
    __shared__ float sY[8];
    ((float4*)&sP[slot][lane * 4])[0] = acc;
    if (t < 8) {
        float a = cA[96], c = cC[96], s = 0.f;
        for (int n = s0 + t; n < s1; n += 8) {
            float v = fmaf(a, y3[n], c);
            s += v > 0.f ? v : 0.f;
        }
        sY[t] = s;
    }
    __syncthreads();
    __shared__ float hg[129];
    __shared__ float hid1[128];
    __shared__ float hid2[64];
    float inv = (s1 > s0) ? 1.f / (float)(s1 - s0) : 1.f;
    if (t < 128) {
        float S = 0.f;
#pragma unroll
        for (int s = 0; s < 8; s++) S += sP[s][t];
        hg[t] = S * inv;
    } else if (t == 128) {
        float S = 0.f;
#pragma unroll
        for (int s = 0; s < 8; s++) S += sY[s];
        hg[128] = S * inv;
    }
    __syncthreads();
    if (t < 128) {
        float a = b0[t];
        for (int i = 0; i < 129; i++) a += hg[i] * w0[i * 128 + t];
        hid1[t] = a > 0.f ? a : 0.f;
    }
    __syncthreads();
    if (t < 64) {
        float a = b1[t];
        for (int i = 0; i < 128; i++) a += hid1[i] * w1[i * 64 + t];
        hid2[t] = a > 0.f ? a : 0.f;
    }
    __syncthreads();
    if (t < 64) {
        float v = hid2[t] * w2[t];
        for (int off = 32; off > 0; off >>= 1) v += __shfl_down(v, off, 64);
        if (t == 0) out[g] = v + b2[0];
    }
}

// ---------------- launcher ----------------

extern "C" void kernel_launch(void* const* d_in, const int* in_sizes, int n_in,
                              void* d_out, int out_size, void* d_ws, size_t ws_size,
                              hipStream_t stream) {
    const float* h   = (const float*)d_in[0];
    const int* src   = (const int*)d_in[1];
    const int* dst   = (const int*)d_in[2];
    const int* gid   = (const int*)d_in[3];
    const float* convw[4], *convb[4], *bng[4], *bnb[4];
    for (int i = 0; i < 4; i++) {
        convw[i] = (const float*)d_in[4 + 4 * i];
        convb[i] = (const float*)d_in[5 + 4 * i];
        bng[i]   = (const float*)d_in[6 + 4 * i];
        bnb[i]   = (const float*)d_in[7 + 4 * i];
    }
    const float* mw0 = (const float*)d_in[20];
    const float* mb0 = (const float*)d_in[21];
    const float* mw1 = (const float*)d_in[22];
    const float* mb1 = (const float*)d_in[23];
    const float* mw2 = (const float*)d_in[24];
    const float* mb2 = (const float*)d_in[25];

    const int N = in_sizes[0] / 32;
    const int E = in_sizes[1];
    const int G = out_size;
    const int NBUCK = cdiv_h(N, BKN);

    // workspace bump allocator (512B aligned)
    char* ws = (char*)d_ws;
    size_t off = 0;
    auto alloc = [&](size_t bytes) -> void* {
        void* p = ws + off;
        off += (bytes + 511) & ~(size_t)511;
        return p;
    };
    int* bcnt      = (int*)alloc((size_t)NBUCK * NPART * 16 * 4);  // 1 counter / 64B line
    unsigned* ebuf = (unsigned*)alloc((size_t)NBUCK * NPART * CAP_P * 4);
    int* col       = (int*)alloc((size_t)NBUCK * CAP * 4);
    int* rs        = (int*)alloc((size_t)N * 4);
    int* re        = (int*)alloc((size_t)N * 4);
    int* gstart    = (int*)alloc((size_t)(G + 1) * 4);
    float* p    = (float*)alloc((size_t)N * 32 * 4);
    float* y0   = (float*)alloc((size_t)N * 32 * 4);
    float* y1   = (float*)alloc((size_t)N * 32 * 4);
    float* y2   = (float*)alloc((size_t)N * 32 * 4);
    float* y3   = (float*)alloc((size_t)N * 4);
    float* sSum = (float*)alloc((size_t)4 * NSLOT * 32 * 4);
    float* sSq  = (float*)alloc((size_t)4 * NSLOT * 32 * 4);
    float* cAa  = (float*)alloc((size_t)4 * 32 * 4);
    float* cCc  = (float*)alloc((size_t)4 * 32 * 4);
    (void)ws_size; (void)n_in;

    const int NB_E = cdiv_h(E, 256);
    const int NB_N = cdiv_h(N, 256);
    const int NB_AG = cdiv_h(N, 32);   // one node per 8-lane group
    const float invN = 1.f / (float)N;

    hipMemsetAsync(bcnt, 0, (size_t)NBUCK * NPART * 16 * 4, stream);
    hipMemsetAsync(sSum, 0, (size_t)4 * NSLOT * 32 * 4, stream);
    hipMemsetAsync(sSq, 0, (size_t)4 * NSLOT * 32 * 4, stream);

    // edge grouping: partitioned bucket append + per-bucket counting sort
    k_bucket_scatter<<<NB_E, 256, 0, stream>>>(src, dst, bcnt, ebuf, E);
    k_local_sort<<<NBUCK, 256, 0, stream>>>(ebuf, bcnt, col, rs, re, N);
    k_gstart<<<NB_N, 256, 0, stream>>>(gid, gstart, N, G);

    // layer 0
    k_transform<0><<<NB_N, 256, 0, stream>>>(h, convw[0], nullptr, nullptr, p, N);
    k_aggregate<<<NB_AG, 256, 0, stream>>>((const float4*)p, rs, re, col, convb[0], (float4*)y0,
                                           sSum + 0 * NSLOT * 32, sSq + 0 * NSLOT * 32, N);
    k_stats<<<1, 32, 0, stream>>>(sSum + 0 * NSLOT * 32, sSq + 0 * NSLOT * 32, bng[0], bnb[0], cAa + 0, cCc + 0, 32, invN);
    // layer 1
    k_transform<1><<<NB_N, 256, 0, stream>>>(y0, convw[1], cAa + 0, cCc + 0, p, N);
    k_aggregate<<<NB_AG, 256, 0, stream>>>((const float4*)p, rs, re, col, convb[1], (float4*)y1,
                                           sSum + 1 * NSLOT * 32, sSq + 1 * NSLOT * 32, N);
    k_stats<<<1, 32, 0, stream>>>(sSum + 1 * NSLOT * 32, sSq + 1 * NSLOT * 32, bng[1], bnb[1], cAa + 32, cCc + 32, 32, invN);
    // layer 2
    k_transform<1><<<NB_N, 256, 0, stream>>>(y1, convw[2], cAa + 32, cCc + 32, p, N);
    k_aggregate<<<NB_AG, 256, 0, stream>>>((const float4*)p, rs, re, col, convb[2], (float4*)y2,
                                           sSum + 2 * NSLOT * 32, sSq + 2 * NSLOT * 32, N);
    k_stats<<<1, 32, 0, stream>>>(sSum + 2 * NSLOT * 32, sSq + 2 * NSLOT * 32, bng[2], bnb[2], cAa + 64, cCc + 64, 32, invN);
    // layer 3 (32 -> 1, pre-multiplied so the gather is scalar)
    k_transform3<<<NB_N, 256, 0, stream>>>(y2, convw[3], cAa + 64, cCc + 64, (float*)p, N);
    k_aggregate3<<<NB_N, 256, 0, stream>>>((float*)p, rs, re, col, convb[3], y3,
                                           sSum + 3 * NSLOT * 32, sSq + 3 * NSLOT * 32, N);
    k_stats<<<1, 32, 0, stream>>>(sSum + 3 * NSLOT * 32, sSq + 3 * NSLOT * 32, bng[3], bnb[3], cAa + 96, cCc + 96, 1, invN);

    // pooling + MLP
    k_pool_mlp<<<G, 256, 0, stream>>>(h, y0, y1, y2, y3, cAa, cCc, gstart,
                                      mw0, mb0, mw1, mb1, mw2, mb2, (float*)d_out);
}